// Round 4
// baseline (1033.349 us; speedup 1.0000x reference)
//
#include <hip/hip_runtime.h>
#include <hip/hip_bf16.h>
#include <cstdint>
#include <cstddef>

typedef __bf16 bf16;
typedef __attribute__((ext_vector_type(8))) __bf16 bf16x8;
typedef __attribute__((ext_vector_type(4))) float f32x4;

static_assert(sizeof(bf16x8) == 16, "bf16x8 must be 16B");

#define NTASK 34
#define BTOT 16384

__device__ __forceinline__ f32x4 mfma16(bf16x8 a, bf16x8 b, f32x4 c) {
  return __builtin_amdgcn_mfma_f32_16x16x32_bf16(a, b, c, 0, 0, 0);
}

__device__ __forceinline__ void gload_lds16(const void* g, void* l) {
  __builtin_amdgcn_global_load_lds((__attribute__((address_space(1))) void*)g,
                                   (__attribute__((address_space(3))) void*)l,
                                   16, 0, 0);
}

__device__ __forceinline__ unsigned pack2(float lo, float hi) {
  union { __bf16 h[2]; unsigned u; } v;
  v.h[0] = (__bf16)lo; v.h[1] = (__bf16)hi;
  return v.u;
}

// ---------------- prep kernels ----------------

// Weights -> bf16 MFMA-fragment chunks (per-task stream of 16 x 8KB):
// chunk (n*16 + phase0 + ks), elem (ct*64+l)*8+j holds
// W[n][k=ks*32+(l>>4)*8+j][col=ct*16+(l&15)]
__global__ void prep_w(const float* __restrict__ src, bf16* __restrict__ dst,
                       int ksteps, int phase0, int total) {
  int idx = blockIdx.x * 256 + threadIdx.x;
  if (idx >= total) return;
  int per_n = ksteps * 512;
  int n = idx / per_n;
  int r = idx - n * per_n;
  int ks = r >> 9;
  int ct = (r >> 6) & 7;
  int l = r & 63;
  int k0 = ks * 32 + ((l >> 4) << 3);
  int col = ct * 16 + (l & 15);
  const float* s = src + ((size_t)n * (ksteps * 32) + k0) * 128 + col;
  bf16x8 v;
#pragma unroll
  for (int j = 0; j < 8; ++j) v[j] = (bf16)s[(size_t)j * 128];
  size_t chunk = (size_t)n * 16 + phase0 + ks;
  *(bf16x8*)(dst + chunk * 4096 + (ct * 64 + l) * 8) = v;
}

// state -> bf16 A/B-fragment order per 16-row strip
__global__ void prep_state_frags(const float* __restrict__ state, bf16* __restrict__ dst) {
  int idx = blockIdx.x * 256 + threadIdx.x;   // 524288 total
  int strip = idx >> 9;
  int r = idx & 511;
  int ks = r >> 6;
  int l = r & 63;
  int b = strip * 16 + (l & 15);
  int k0 = ks * 32 + ((l >> 4) << 3);
  const float* s = state + (size_t)b * 256 + k0;
  bf16x8 v;
#pragma unroll
  for (int j = 0; j < 8; ++j) v[j] = (bf16)s[j];
  *(bf16x8*)(dst + (size_t)idx * 8) = v;
}

__global__ void prep_langn(const float* __restrict__ lang, float* __restrict__ out) {
  __shared__ float red[2];
  int n = blockIdx.x;
  int t = threadIdx.x;
  float v = lang[(size_t)n * 128 + t];
  float ss = v * v;
#pragma unroll
  for (int m = 1; m < 64; m <<= 1) ss += __shfl_xor(ss, m);
  if ((t & 63) == 0) red[t >> 6] = ss;
  __syncthreads();
  float s = red[0] + red[1];
  float sc = 1.0f / fmaxf(sqrtf(s), 1e-8f);
  out[(size_t)n * 128 + t] = v * sc;
}

// softmax(prior) -> f32 transposed pp_t[34][B]
__global__ void prep_pprior(const float* __restrict__ prior, float* __restrict__ ppt) {
  int row = blockIdx.x * 4 + (threadIdx.x >> 6);
  int lane = threadIdx.x & 63;
  float v = (lane < NTASK) ? prior[(size_t)row * NTASK + lane] : -INFINITY;
  float m = v;
#pragma unroll
  for (int mm = 1; mm < 64; mm <<= 1) m = fmaxf(m, __shfl_xor(m, mm));
  float e = (lane < NTASK) ? expf(v - m) : 0.0f;
  float s = e;
#pragma unroll
  for (int mm = 1; mm < 64; mm <<= 1) s += __shfl_xor(s, mm);
  if (lane < NTASK) ppt[(size_t)lane * BTOT + row] = e / s;
}

// ---------------- pass 1: barrier-free swapped-MFMA ----------------
// grid: blk = rg*34 + n  (rg = 64-strip row group of 256 rows; n = task)
// 8 waves x 32 rows each; wave owns its rows end-to-end, no mid-loop barriers.

__global__ void __launch_bounds__(512, 2)
pass1_kernel(const int* __restrict__ task_id,
             const float* __restrict__ b1, const float* __restrict__ b2,
             const float* __restrict__ b3,
             const bf16* __restrict__ wstream, const bf16* __restrict__ sf,
             const float* __restrict__ langn, const float* __restrict__ ppt,
             float* __restrict__ cs_t, float* __restrict__ lat_ws,
             float* __restrict__ out_tgt) {
  __shared__ __align__(16) bf16 shW[16 * 4096];   // this task's weights, 128KB
  __shared__ __align__(16) float shB[3][128];     // biases

  const int tid = threadIdx.x;
  const int l = tid & 63;
  const int w = tid >> 6;
  const int g4 = l >> 4;
  const int r16 = l & 15;
  const int blk = blockIdx.x;
  const int n = blk % NTASK;
  const int rg = blk / NTASK;
  const int rowbase = rg * 256 + w * 32;

  // ---- prologue: stage weights + biases, load state frags / row meta
  const bf16* wbase = wstream + (size_t)n * 65536;
#pragma unroll
  for (int c = 0; c < 16; ++c)
    gload_lds16(wbase + c * 4096 + tid * 8, shW + c * 4096 + tid * 8);
  if (tid < 128) {
    shB[0][tid] = b1[n * 128 + tid];
    shB[1][tid] = b2[n * 128 + tid];
    shB[2][tid] = b3[n * 128 + tid];
  }

  bf16x8 sfrag[2][8];
#pragma unroll
  for (int rt = 0; rt < 2; ++rt) {
    const bf16* sp = sf + (size_t)(rg * 16 + w * 2 + rt) * 4096 + l * 8;
#pragma unroll
    for (int ks = 0; ks < 8; ++ks)
      sfrag[rt][ks] = *(const bf16x8*)(sp + ks * 512);
  }
  int tidr[2]; float pw[2];
#pragma unroll
  for (int rt = 0; rt < 2; ++rt) {
    int row = rowbase + rt * 16 + r16;
    tidr[rt] = task_id[row];
    pw[rt] = ppt[(size_t)n * BTOT + row];
  }
  __syncthreads();   // the only block-wide barrier

  const f32x4 fz = {0.f, 0.f, 0.f, 0.f};
  const int srcA = (g4 & 1) * 32 + r16;   // shfl source lane base
  const int hsel = g4 >> 1;               // which hc-half to take

  // ---- GEMM1 (swapped): T1[hcol][b] = W1^T . state^T, chunks 0..7
  f32x4 a1[2][8];
#pragma unroll
  for (int rt = 0; rt < 2; ++rt)
#pragma unroll
    for (int hc = 0; hc < 8; ++hc) a1[rt][hc] = fz;
#pragma unroll
  for (int ks = 0; ks < 8; ++ks) {
#pragma unroll
    for (int hc = 0; hc < 8; ++hc) {
      bf16x8 wf = *(const bf16x8*)(shW + ks * 4096 + hc * 512 + l * 8);
      a1[0][hc] = mfma16(wf, sfrag[0][ks], a1[0][hc]);
      a1[1][hc] = mfma16(wf, sfrag[1][ks], a1[1][hc]);
    }
  }
  // h1 = relu(T1 + b1), pack to bf16 pairs (lane-local)
  unsigned pk[2][8][2];
#pragma unroll
  for (int hc = 0; hc < 8; ++hc) {
    float4 bv = *(const float4*)&shB[0][hc * 16 + g4 * 4];
#pragma unroll
    for (int rt = 0; rt < 2; ++rt) {
      float h0 = fmaxf(a1[rt][hc][0] + bv.x, 0.f);
      float h1 = fmaxf(a1[rt][hc][1] + bv.y, 0.f);
      float h2 = fmaxf(a1[rt][hc][2] + bv.z, 0.f);
      float h3 = fmaxf(a1[rt][hc][3] + bv.w, 0.f);
      pk[rt][hc][0] = pack2(h0, h1);
      pk[rt][hc][1] = pack2(h2, h3);
    }
  }

  // ---- GEMM2 (swapped): chunks 8..11, B-frags assembled via register shfl
  f32x4 a2[2][8];
#pragma unroll
  for (int rt = 0; rt < 2; ++rt)
#pragma unroll
    for (int hc = 0; hc < 8; ++hc) a2[rt][hc] = fz;
#pragma unroll
  for (int ks = 0; ks < 4; ++ks) {
    bf16x8 hb[2];
#pragma unroll
    for (int rt = 0; rt < 2; ++rt) {
      union { unsigned u[4]; bf16x8 v; } asm_u;
#pragma unroll
      for (int m = 0; m < 4; ++m) {
        int src = srcA + (m >> 1) * 16;
        unsigned lo = __shfl(pk[rt][2 * ks][m & 1], src);
        unsigned hi = __shfl(pk[rt][2 * ks + 1][m & 1], src);
        asm_u.u[m] = hsel ? hi : lo;
      }
      hb[rt] = asm_u.v;
    }
#pragma unroll
    for (int hc = 0; hc < 8; ++hc) {
      bf16x8 wf = *(const bf16x8*)(shW + (8 + ks) * 4096 + hc * 512 + l * 8);
      a2[0][hc] = mfma16(wf, hb[0], a2[0][hc]);
      a2[1][hc] = mfma16(wf, hb[1], a2[1][hc]);
    }
  }
  // h2 = relu(T2 + b2), pack
#pragma unroll
  for (int hc = 0; hc < 8; ++hc) {
    float4 bv = *(const float4*)&shB[1][hc * 16 + g4 * 4];
#pragma unroll
    for (int rt = 0; rt < 2; ++rt) {
      float h0 = fmaxf(a2[rt][hc][0] + bv.x, 0.f);
      float h1 = fmaxf(a2[rt][hc][1] + bv.y, 0.f);
      float h2 = fmaxf(a2[rt][hc][2] + bv.z, 0.f);
      float h3 = fmaxf(a2[rt][hc][3] + bv.w, 0.f);
      pk[rt][hc][0] = pack2(h0, h1);
      pk[rt][hc][1] = pack2(h2, h3);
    }
  }

  // ---- GEMM3 (swapped): chunks 12..15
  f32x4 a3[2][8];
#pragma unroll
  for (int rt = 0; rt < 2; ++rt)
#pragma unroll
    for (int hc = 0; hc < 8; ++hc) a3[rt][hc] = fz;
#pragma unroll
  for (int ks = 0; ks < 4; ++ks) {
    bf16x8 hb[2];
#pragma unroll
    for (int rt = 0; rt < 2; ++rt) {
      union { unsigned u[4]; bf16x8 v; } asm_u;
#pragma unroll
      for (int m = 0; m < 4; ++m) {
        int src = srcA + (m >> 1) * 16;
        unsigned lo = __shfl(pk[rt][2 * ks][m & 1], src);
        unsigned hi = __shfl(pk[rt][2 * ks + 1][m & 1], src);
        asm_u.u[m] = hsel ? hi : lo;
      }
      hb[rt] = asm_u.v;
    }
#pragma unroll
    for (int hc = 0; hc < 8; ++hc) {
      bf16x8 wf = *(const bf16x8*)(shW + (12 + ks) * 4096 + hc * 512 + l * 8);
      a3[0][hc] = mfma16(wf, hb[0], a3[0][hc]);
      a3[1][hc] = mfma16(wf, hb[1], a3[1][hc]);
    }
  }

  // ---- epilogue: per-lane full row slice (32 of 128 cols), 2-shfl reductions
#pragma unroll
  for (int rt = 0; rt < 2; ++rt) {
    int row = rowbase + rt * 16 + r16;
    // q = T3 + b3 (keep in a3), partial ssq/dot over this lane's 32 cols
    float ssq = 0.f, dot = 0.f;
#pragma unroll
    for (int hc = 0; hc < 8; ++hc) {
      float4 bv = *(const float4*)&shB[2][hc * 16 + g4 * 4];
      float4 lg = *(const float4*)&langn[(size_t)tidr[rt] * 128 + hc * 16 + g4 * 4];
      a3[rt][hc][0] += bv.x; a3[rt][hc][1] += bv.y;
      a3[rt][hc][2] += bv.z; a3[rt][hc][3] += bv.w;
      ssq += a3[rt][hc][0] * a3[rt][hc][0] + a3[rt][hc][1] * a3[rt][hc][1]
           + a3[rt][hc][2] * a3[rt][hc][2] + a3[rt][hc][3] * a3[rt][hc][3];
      dot += a3[rt][hc][0] * lg.x + a3[rt][hc][1] * lg.y
           + a3[rt][hc][2] * lg.z + a3[rt][hc][3] * lg.w;
    }
    ssq += __shfl_xor(ssq, 16); ssq += __shfl_xor(ssq, 32);
    dot += __shfl_xor(dot, 16); dot += __shfl_xor(dot, 32);
    float inv = rsqrtf(ssq);
    if (g4 == 0) cs_t[(size_t)n * BTOT + row] = dot * inv;
    float pwf = pw[rt];
    bool is_tgt = (tidr[rt] == n);
#pragma unroll
    for (int hc = 0; hc < 8; ++hc) {
      float q0 = a3[rt][hc][0] * inv, q1 = a3[rt][hc][1] * inv;
      float q2 = a3[rt][hc][2] * inv, q3 = a3[rt][hc][3] * inv;
      size_t base = (size_t)row * 128 + hc * 16 + g4 * 4;
      if (is_tgt) {
        float4 qv = {q0, q1, q2, q3};
        *(float4*)&out_tgt[base] = qv;
      }
      atomicAdd(&lat_ws[base + 0], pwf * q0);
      atomicAdd(&lat_ws[base + 1], pwf * q1);
      atomicAdd(&lat_ws[base + 2], pwf * q2);
      atomicAdd(&lat_ws[base + 3], pwf * q3);
    }
  }
}

// ---------------- pass 3: per-row combine ----------------

__global__ void __launch_bounds__(256)
pass3_kernel(const float* __restrict__ state, const float* __restrict__ cs_t,
             const float* __restrict__ lat_ws,
             float* __restrict__ out_rep, float* __restrict__ out_ltp,
             float* __restrict__ out_lat) {
  int w = threadIdx.x >> 6, l = threadIdx.x & 63;
  size_t row = (size_t)blockIdx.x * 4 + w;
  float c = (l < NTASK) ? cs_t[(size_t)l * BTOT + row] * 10.0f : -1e30f;
  float m = c;
#pragma unroll
  for (int mm = 1; mm < 64; mm <<= 1) m = fmaxf(m, __shfl_xor(m, mm));
  float e = (l < NTASK) ? expf(c - m) : 0.0f;
  float s = e;
#pragma unroll
  for (int mm = 1; mm < 64; mm <<= 1) s += __shfl_xor(s, mm);
  float lse = logf(s);
  if (l < NTASK) out_ltp[row * NTASK + l] = c - m - lse;
  float2 lv = *(const float2*)(lat_ws + row * 128 + l * 2);
  *(float2*)(out_lat + row * 128 + l * 2) = lv;
  *(float2*)(out_rep + row * 384 + 256 + l * 2) = lv;
  float4 sv = *(const float4*)(state + row * 256 + l * 4);
  *(float4*)(out_rep + row * 384 + l * 4) = sv;
}

// ---------------- launch ----------------

extern "C" void kernel_launch(void* const* d_in, const int* in_sizes, int n_in,
                              void* d_out, int out_size, void* d_ws, size_t ws_size,
                              hipStream_t stream) {
  (void)in_sizes; (void)n_in; (void)out_size; (void)ws_size;
  const float* state = (const float*)d_in[0];
  const int* task_id = (const int*)d_in[1];
  const float* prior = (const float*)d_in[2];
  const float* W1 = (const float*)d_in[3];
  const float* b1 = (const float*)d_in[4];
  const float* W2 = (const float*)d_in[5];
  const float* b2 = (const float*)d_in[6];
  const float* W3 = (const float*)d_in[7];
  const float* b3 = (const float*)d_in[8];
  const float* lang = (const float*)d_in[9];

  char* ws = (char*)d_ws;
  bf16* wstream = (bf16*)(ws + 0);          //  4,456,448 B
  bf16* sf      = (bf16*)(ws + 4456448);    //  8,388,608 B
  float* langn  = (float*)(ws + 12845056);  //     17,408 B
  float* ppt    = (float*)(ws + 12862464);  //  2,228,224 B  [34][16384] f32
  float* cs_t   = (float*)(ws + 15090688);  //  2,228,224 B  [34][16384] f32
  float* lat_ws = (float*)(ws + 17318912);  //  8,388,608 B  (ends 25,707,520)

  float* out = (float*)d_out;
  float* out_rep = out;                 // [B,384]
  float* out_ltp = out + 6291456;       // [B,34]
  float* out_tgt = out + 6848512;       // [B,128]
  float* out_lat = out + 8945664;       // [B,128]

  hipMemsetAsync(lat_ws, 0, 8388608, stream);
  prep_w<<<544, 256, 0, stream>>>(W1, wstream, 8, 0, NTASK * 8 * 512);
  prep_w<<<272, 256, 0, stream>>>(W2, wstream, 4, 8, NTASK * 4 * 512);
  prep_w<<<272, 256, 0, stream>>>(W3, wstream, 4, 12, NTASK * 4 * 512);
  prep_state_frags<<<2048, 256, 0, stream>>>(state, sf);
  prep_langn<<<NTASK, 128, 0, stream>>>(lang, langn);
  prep_pprior<<<4096, 256, 0, stream>>>(prior, ppt);
  pass1_kernel<<<64 * NTASK, 512, 0, stream>>>(task_id, b1, b2, b3, wstream, sf,
                                               langn, ppt, cs_t, lat_ws, out_tgt);
  pass3_kernel<<<4096, 256, 0, stream>>>(state, cs_t, lat_ws,
                                         out_rep, out_ltp, out_lat);
}

// Round 5
// 207.142 us; speedup vs baseline: 4.9886x; 4.9886x over previous
//
#include <hip/hip_runtime.h>
#include <hip/hip_bf16.h>
#include <cstdint>
#include <cstddef>

typedef __bf16 bf16;
typedef __attribute__((ext_vector_type(8))) __bf16 bf16x8;
typedef __attribute__((ext_vector_type(4))) float f32x4;

static_assert(sizeof(bf16x8) == 16, "bf16x8 must be 16B");

#define NTASK 34
#define BTOT 16384

__device__ __forceinline__ f32x4 mfma16(bf16x8 a, bf16x8 b, f32x4 c) {
  return __builtin_amdgcn_mfma_f32_16x16x32_bf16(a, b, c, 0, 0, 0);
}

__device__ __forceinline__ void gload_lds16(const void* g, void* l) {
  __builtin_amdgcn_global_load_lds((__attribute__((address_space(1))) void*)g,
                                   (__attribute__((address_space(3))) void*)l,
                                   16, 0, 0);
}

__device__ __forceinline__ unsigned pack2(float lo, float hi) {
  union { __bf16 h[2]; unsigned u; } v;
  v.h[0] = (__bf16)lo; v.h[1] = (__bf16)hi;
  return v.u;
}

// ---------------- prep kernels ----------------

// Weights -> bf16 MFMA-fragment chunks (per-task stream of 16 x 8KB):
// chunk (n*16 + phase0 + ks), elem (ct*64+l)*8+j holds
// W[n][k=ks*32+(l>>4)*8+j][col=ct*16+(l&15)]
__global__ void prep_w(const float* __restrict__ src, bf16* __restrict__ dst,
                       int ksteps, int phase0, int total) {
  int idx = blockIdx.x * 256 + threadIdx.x;
  if (idx >= total) return;
  int per_n = ksteps * 512;
  int n = idx / per_n;
  int r = idx - n * per_n;
  int ks = r >> 9;
  int ct = (r >> 6) & 7;
  int l = r & 63;
  int k0 = ks * 32 + ((l >> 4) << 3);
  int col = ct * 16 + (l & 15);
  const float* s = src + ((size_t)n * (ksteps * 32) + k0) * 128 + col;
  bf16x8 v;
#pragma unroll
  for (int j = 0; j < 8; ++j) v[j] = (bf16)s[(size_t)j * 128];
  size_t chunk = (size_t)n * 16 + phase0 + ks;
  *(bf16x8*)(dst + chunk * 4096 + (ct * 64 + l) * 8) = v;
}

// state -> bf16 fragment order per 16-row strip
__global__ void prep_state_frags(const float* __restrict__ state, bf16* __restrict__ dst) {
  int idx = blockIdx.x * 256 + threadIdx.x;   // 524288 total
  int strip = idx >> 9;
  int r = idx & 511;
  int ks = r >> 6;
  int l = r & 63;
  int b = strip * 16 + (l & 15);
  int k0 = ks * 32 + ((l >> 4) << 3);
  const float* s = state + (size_t)b * 256 + k0;
  bf16x8 v;
#pragma unroll
  for (int j = 0; j < 8; ++j) v[j] = (bf16)s[j];
  *(bf16x8*)(dst + (size_t)idx * 8) = v;
}

__global__ void prep_langn(const float* __restrict__ lang, float* __restrict__ out) {
  __shared__ float red[2];
  int n = blockIdx.x;
  int t = threadIdx.x;
  float v = lang[(size_t)n * 128 + t];
  float ss = v * v;
#pragma unroll
  for (int m = 1; m < 64; m <<= 1) ss += __shfl_xor(ss, m);
  if ((t & 63) == 0) red[t >> 6] = ss;
  __syncthreads();
  float s = red[0] + red[1];
  float sc = 1.0f / fmaxf(sqrtf(s), 1e-8f);
  out[(size_t)n * 128 + t] = v * sc;
}

// ---------------- pass 1: high-occupancy barrier-free swapped-MFMA ----------------
// grid: blk = n*32 + rg (task-major). 1024 threads = 16 waves (4/SIMD).
// Each wave owns 32 rows end-to-end; LDS only for weights+biases; no atomics.

__global__ void __launch_bounds__(1024, 4)
pass1_kernel(const int* __restrict__ task_id,
             const float* __restrict__ b1, const float* __restrict__ b2,
             const float* __restrict__ b3,
             const bf16* __restrict__ wstream, const bf16* __restrict__ sf,
             const float* __restrict__ langn,
             float* __restrict__ cs_t, bf16* __restrict__ q_store) {
  __shared__ __align__(16) bf16 shW[16 * 4096];   // this task's weights, 128KB
  __shared__ __align__(16) float shB[3][128];     // biases

  const int tid = threadIdx.x;
  const int l = tid & 63;
  const int w = tid >> 6;                 // wave 0..15
  const int g4 = l >> 4;
  const int r16 = l & 15;
  const int blk = blockIdx.x;
  const int n = blk >> 5;                 // task
  const int rg = blk & 31;                // row group of 512
  const int rowbase = rg * 512 + w * 32;

  // ---- prologue: stage 128KB weights (8 rounds x 16KB), biases, state frags
  const bf16* wbase = wstream + (size_t)n * 65536;
#pragma unroll
  for (int r = 0; r < 8; ++r)
    gload_lds16(wbase + r * 8192 + tid * 8, shW + r * 8192 + tid * 8);
  if (tid < 128) shB[0][tid] = b1[n * 128 + tid];
  else if (tid < 256) shB[1][tid - 128] = b2[n * 128 + (tid - 128)];
  else if (tid < 384) shB[2][tid - 256] = b3[n * 128 + (tid - 256)];

  bf16x8 sfrag[2][8];
#pragma unroll
  for (int rt = 0; rt < 2; ++rt) {
    const bf16* sp = sf + (size_t)(rg * 32 + w * 2 + rt) * 4096 + l * 8;
#pragma unroll
    for (int ks = 0; ks < 8; ++ks)
      sfrag[rt][ks] = *(const bf16x8*)(sp + ks * 512);
  }
  int tidr[2];
#pragma unroll
  for (int rt = 0; rt < 2; ++rt)
    tidr[rt] = task_id[rowbase + rt * 16 + r16];
  __syncthreads();   // the only block-wide barrier

  const f32x4 fz = {0.f, 0.f, 0.f, 0.f};
  const int srcA = (g4 & 1) * 32 + r16;   // shfl source lane base
  const int hsel = g4 >> 1;               // which hc-half to take

  // ---- GEMM1 (swapped): T1[hcol][b] = W1^T . state^T, chunks 0..7
  f32x4 a1[2][8];
#pragma unroll
  for (int rt = 0; rt < 2; ++rt)
#pragma unroll
    for (int hc = 0; hc < 8; ++hc) a1[rt][hc] = fz;
#pragma unroll
  for (int ks = 0; ks < 8; ++ks) {
#pragma unroll
    for (int hc = 0; hc < 8; ++hc) {
      bf16x8 wf = *(const bf16x8*)(shW + ks * 4096 + hc * 512 + l * 8);
      a1[0][hc] = mfma16(wf, sfrag[0][ks], a1[0][hc]);
      a1[1][hc] = mfma16(wf, sfrag[1][ks], a1[1][hc]);
    }
  }
  // h1 = relu(T1 + b1), pack to bf16 pairs (lane-local)
  unsigned pk[2][8][2];
#pragma unroll
  for (int hc = 0; hc < 8; ++hc) {
    float4 bv = *(const float4*)&shB[0][hc * 16 + g4 * 4];
#pragma unroll
    for (int rt = 0; rt < 2; ++rt) {
      float h0 = fmaxf(a1[rt][hc][0] + bv.x, 0.f);
      float h1 = fmaxf(a1[rt][hc][1] + bv.y, 0.f);
      float h2 = fmaxf(a1[rt][hc][2] + bv.z, 0.f);
      float h3 = fmaxf(a1[rt][hc][3] + bv.w, 0.f);
      pk[rt][hc][0] = pack2(h0, h1);
      pk[rt][hc][1] = pack2(h2, h3);
    }
  }

  // ---- GEMM2 (swapped): chunks 8..11, B-frags assembled via register shfl
  f32x4 a2[2][8];
#pragma unroll
  for (int rt = 0; rt < 2; ++rt)
#pragma unroll
    for (int hc = 0; hc < 8; ++hc) a2[rt][hc] = fz;
#pragma unroll
  for (int ks = 0; ks < 4; ++ks) {
    bf16x8 hb[2];
#pragma unroll
    for (int rt = 0; rt < 2; ++rt) {
      union { unsigned u[4]; bf16x8 v; } asm_u;
#pragma unroll
      for (int m = 0; m < 4; ++m) {
        int src = srcA + (m >> 1) * 16;
        unsigned lo = __shfl(pk[rt][2 * ks][m & 1], src);
        unsigned hi = __shfl(pk[rt][2 * ks + 1][m & 1], src);
        asm_u.u[m] = hsel ? hi : lo;
      }
      hb[rt] = asm_u.v;
    }
#pragma unroll
    for (int hc = 0; hc < 8; ++hc) {
      bf16x8 wf = *(const bf16x8*)(shW + (8 + ks) * 4096 + hc * 512 + l * 8);
      a2[0][hc] = mfma16(wf, hb[0], a2[0][hc]);
      a2[1][hc] = mfma16(wf, hb[1], a2[1][hc]);
    }
  }
  // h2 = relu(T2 + b2), pack
#pragma unroll
  for (int hc = 0; hc < 8; ++hc) {
    float4 bv = *(const float4*)&shB[1][hc * 16 + g4 * 4];
#pragma unroll
    for (int rt = 0; rt < 2; ++rt) {
      float h0 = fmaxf(a2[rt][hc][0] + bv.x, 0.f);
      float h1 = fmaxf(a2[rt][hc][1] + bv.y, 0.f);
      float h2 = fmaxf(a2[rt][hc][2] + bv.z, 0.f);
      float h3 = fmaxf(a2[rt][hc][3] + bv.w, 0.f);
      pk[rt][hc][0] = pack2(h0, h1);
      pk[rt][hc][1] = pack2(h2, h3);
    }
  }

  // ---- GEMM3 (swapped): chunks 12..15
  f32x4 a3[2][8];
#pragma unroll
  for (int rt = 0; rt < 2; ++rt)
#pragma unroll
    for (int hc = 0; hc < 8; ++hc) a3[rt][hc] = fz;
#pragma unroll
  for (int ks = 0; ks < 4; ++ks) {
    bf16x8 hb[2];
#pragma unroll
    for (int rt = 0; rt < 2; ++rt) {
      union { unsigned u[4]; bf16x8 v; } asm_u;
#pragma unroll
      for (int m = 0; m < 4; ++m) {
        int src = srcA + (m >> 1) * 16;
        unsigned lo = __shfl(pk[rt][2 * ks][m & 1], src);
        unsigned hi = __shfl(pk[rt][2 * ks + 1][m & 1], src);
        asm_u.u[m] = hsel ? hi : lo;
      }
      hb[rt] = asm_u.v;
    }
#pragma unroll
    for (int hc = 0; hc < 8; ++hc) {
      bf16x8 wf = *(const bf16x8*)(shW + (12 + ks) * 4096 + hc * 512 + l * 8);
      a3[0][hc] = mfma16(wf, hb[0], a3[0][hc]);
      a3[1][hc] = mfma16(wf, hb[1], a3[1][hc]);
    }
  }

  // ---- epilogue: q = (T3+b3)/||.||; cs_t + bf16 q_store (plain stores)
#pragma unroll
  for (int rt = 0; rt < 2; ++rt) {
    int row = rowbase + rt * 16 + r16;
    float ssq = 0.f, dot = 0.f;
#pragma unroll
    for (int hc = 0; hc < 8; ++hc) {
      float4 bv = *(const float4*)&shB[2][hc * 16 + g4 * 4];
      float4 lg = *(const float4*)&langn[(size_t)tidr[rt] * 128 + hc * 16 + g4 * 4];
      a3[rt][hc][0] += bv.x; a3[rt][hc][1] += bv.y;
      a3[rt][hc][2] += bv.z; a3[rt][hc][3] += bv.w;
      ssq += a3[rt][hc][0] * a3[rt][hc][0] + a3[rt][hc][1] * a3[rt][hc][1]
           + a3[rt][hc][2] * a3[rt][hc][2] + a3[rt][hc][3] * a3[rt][hc][3];
      dot += a3[rt][hc][0] * lg.x + a3[rt][hc][1] * lg.y
           + a3[rt][hc][2] * lg.z + a3[rt][hc][3] * lg.w;
    }
    ssq += __shfl_xor(ssq, 16); ssq += __shfl_xor(ssq, 32);
    dot += __shfl_xor(dot, 16); dot += __shfl_xor(dot, 32);
    float inv = rsqrtf(ssq);
    if (g4 == 0) cs_t[(size_t)n * BTOT + row] = dot * inv;
    bf16* qrow = q_store + ((size_t)n * BTOT + row) * 128;
#pragma unroll
    for (int hc = 0; hc < 8; ++hc) {
      uint2 qp;
      qp.x = pack2(a3[rt][hc][0] * inv, a3[rt][hc][1] * inv);
      qp.y = pack2(a3[rt][hc][2] * inv, a3[rt][hc][3] * inv);
      *(uint2*)(qrow + hc * 16 + g4 * 4) = qp;
    }
  }
}

// ---------------- pass 3: per-row combine (1 wave per row) ----------------

__global__ void __launch_bounds__(256)
pass3_kernel(const float* __restrict__ state, const int* __restrict__ task_id,
             const float* __restrict__ prior, const float* __restrict__ cs_t,
             const bf16* __restrict__ q_store,
             float* __restrict__ out_rep, float* __restrict__ out_ltp,
             float* __restrict__ out_tgt, float* __restrict__ out_lat) {
  __shared__ float spp[4][NTASK];
  int w = threadIdx.x >> 6, l = threadIdx.x & 63;
  size_t row = (size_t)blockIdx.x * 4 + w;

  // softmax(prior) -> spp
  float pv = (l < NTASK) ? prior[row * NTASK + l] : -INFINITY;
  float m = pv;
#pragma unroll
  for (int mm = 1; mm < 64; mm <<= 1) m = fmaxf(m, __shfl_xor(m, mm));
  float e = (l < NTASK) ? expf(pv - m) : 0.0f;
  float s = e;
#pragma unroll
  for (int mm = 1; mm < 64; mm <<= 1) s += __shfl_xor(s, mm);
  if (l < NTASK) spp[w][l] = e / s;

  // log_softmax(cos*10) -> ltp
  float c = (l < NTASK) ? cs_t[(size_t)l * BTOT + row] * 10.0f : -1e30f;
  float cm = c;
#pragma unroll
  for (int mm = 1; mm < 64; mm <<= 1) cm = fmaxf(cm, __shfl_xor(cm, mm));
  float ce = (l < NTASK) ? expf(c - cm) : 0.0f;
  float cs = ce;
#pragma unroll
  for (int mm = 1; mm < 64; mm <<= 1) cs += __shfl_xor(cs, mm);
  if (l < NTASK) out_ltp[row * NTASK + l] = c - cm - logf(cs);
  __syncthreads();

  // latent: lane covers cols {2l, 2l+1}
  float lat0 = 0.f, lat1 = 0.f;
#pragma unroll
  for (int n = 0; n < NTASK; ++n) {
    float pw = spp[w][n];
    union { unsigned u; __bf16 h[2]; } q;
    q.u = *(const unsigned*)(q_store + ((size_t)n * BTOT + row) * 128 + 2 * l);
    lat0 += pw * (float)q.h[0];
    lat1 += pw * (float)q.h[1];
  }
  float2 lv = {lat0, lat1};
  *(float2*)(out_lat + row * 128 + 2 * l) = lv;
  *(float2*)(out_rep + row * 384 + 256 + 2 * l) = lv;

  // latent_target: gather q[task_id[row]]
  int tg = task_id[row];
  union { unsigned u; __bf16 h[2]; } qt;
  qt.u = *(const unsigned*)(q_store + ((size_t)tg * BTOT + row) * 128 + 2 * l);
  float2 tv = {(float)qt.h[0], (float)qt.h[1]};
  *(float2*)(out_tgt + row * 128 + 2 * l) = tv;

  // state passthrough
  float4 sv = *(const float4*)(state + row * 256 + l * 4);
  *(float4*)(out_rep + row * 384 + l * 4) = sv;
}

// ---------------- launch ----------------

extern "C" void kernel_launch(void* const* d_in, const int* in_sizes, int n_in,
                              void* d_out, int out_size, void* d_ws, size_t ws_size,
                              hipStream_t stream) {
  (void)in_sizes; (void)n_in; (void)out_size; (void)ws_size;
  const float* state = (const float*)d_in[0];
  const int* task_id = (const int*)d_in[1];
  const float* prior = (const float*)d_in[2];
  const float* W1 = (const float*)d_in[3];
  const float* b1 = (const float*)d_in[4];
  const float* W2 = (const float*)d_in[5];
  const float* b2 = (const float*)d_in[6];
  const float* W3 = (const float*)d_in[7];
  const float* b3 = (const float*)d_in[8];
  const float* lang = (const float*)d_in[9];

  char* ws = (char*)d_ws;
  bf16* wstream = (bf16*)(ws + 0);          //   4,456,448 B
  bf16* sf      = (bf16*)(ws + 4456448);    //   8,388,608 B
  float* langn  = (float*)(ws + 12845056);  //      17,408 B
  float* cs_t   = (float*)(ws + 12862464);  //   2,228,224 B  [34][16384] f32
  bf16* q_store = (bf16*)(ws + 15090688);   // 142,606,336 B  [34][16384][128] bf16
                                            // total 157,697,024 B

  float* out = (float*)d_out;
  float* out_rep = out;                 // [B,384]
  float* out_ltp = out + 6291456;       // [B,34]
  float* out_tgt = out + 6848512;       // [B,128]
  float* out_lat = out + 8945664;       // [B,128]

  prep_w<<<544, 256, 0, stream>>>(W1, wstream, 8, 0, NTASK * 8 * 512);
  prep_w<<<272, 256, 0, stream>>>(W2, wstream, 4, 8, NTASK * 4 * 512);
  prep_w<<<272, 256, 0, stream>>>(W3, wstream, 4, 12, NTASK * 4 * 512);
  prep_state_frags<<<2048, 256, 0, stream>>>(state, sf);
  prep_langn<<<NTASK, 128, 0, stream>>>(lang, langn);
  pass1_kernel<<<NTASK * 32, 1024, 0, stream>>>(task_id, b1, b2, b3, wstream, sf,
                                                langn, cs_t, q_store);
  pass3_kernel<<<4096, 256, 0, stream>>>(state, task_id, prior, cs_t, q_store,
                                         out_rep, out_ltp, out_tgt, out_lat);
}